// Round 7
// baseline (415.552 us; speedup 1.0000x reference)
//
#include <hip/hip_runtime.h>

#define IMG 512
#define HW (IMG * IMG)
#define NB 32
#define NIMG 64
#define BAND 16
#define NBAND (IMG / BAND)              // 32
#define GRID (NIMG * NBAND)             // 2048
#define NSTG 5                          // fused iterations per launch
#define HALO (2 * NSTG)                 // 10
#define NSTEP ((BAND + 2 * HALO) / 2)   // 18 row-pair steps
#define INF __builtin_inff()

// DPP whole-wave shift-by-1. bound_ctrl=0 keeps `ident` (old) in the vacated lane.
static __device__ __forceinline__ float dpp_from_prev(float v, float ident) {
    return __int_as_float(__builtin_amdgcn_update_dpp(
        __float_as_int(ident), __float_as_int(v), 0x138, 0xF, 0xF, false));
}
static __device__ __forceinline__ float dpp_from_next(float v, float ident) {
    return __int_as_float(__builtin_amdgcn_update_dpp(
        __float_as_int(ident), __float_as_int(v), 0x130, 0xF, 0xF, false));
}

// One lane owns 8 contiguous columns: a = cols[8l..8l+3], b = cols[8l+4..8l+7].
struct Row { float4 a, b; };

static __device__ __forceinline__ float min3f(float a, float b, float c) { return fminf(fminf(a, b), c); }
static __device__ __forceinline__ float max3f(float a, float b, float c) { return fmaxf(fmaxf(a, b), c); }

static __device__ __forceinline__ Row splat(float v) {
    Row r;
    r.a = make_float4(v, v, v, v);
    r.b = make_float4(v, v, v, v);
    return r;
}

static __device__ __forceinline__ Row rmin3(const Row& x, const Row& y, const Row& z) {
    Row o;
    const float* px = (const float*)&x;
    const float* py = (const float*)&y;
    const float* pz = (const float*)&z;
    float* po = (float*)&o;
#pragma unroll
    for (int i = 0; i < 8; ++i) po[i] = min3f(px[i], py[i], pz[i]);
    return o;
}

static __device__ __forceinline__ Row rmax3(const Row& x, const Row& y, const Row& z) {
    Row o;
    const float* px = (const float*)&x;
    const float* py = (const float*)&y;
    const float* pz = (const float*)&z;
    float* po = (float*)&o;
#pragma unroll
    for (int i = 0; i < 8; ++i) po[i] = max3f(px[i], py[i], pz[i]);
    return o;
}

static __device__ __forceinline__ Row hmin3(const Row& v) {
    float shl = dpp_from_prev(v.b.w, INF);
    float shr = dpp_from_next(v.a.x, INF);
    Row o;
    o.a.x = min3f(shl,   v.a.x, v.a.y);
    o.a.y = min3f(v.a.x, v.a.y, v.a.z);
    o.a.z = min3f(v.a.y, v.a.z, v.a.w);
    o.a.w = min3f(v.a.z, v.a.w, v.b.x);
    o.b.x = min3f(v.a.w, v.b.x, v.b.y);
    o.b.y = min3f(v.b.x, v.b.y, v.b.z);
    o.b.z = min3f(v.b.y, v.b.z, v.b.w);
    o.b.w = min3f(v.b.z, v.b.w, shr);
    return o;
}

static __device__ __forceinline__ Row hmax3(const Row& v) {
    float shl = dpp_from_prev(v.b.w, -INF);
    float shr = dpp_from_next(v.a.x, -INF);
    Row o;
    o.a.x = max3f(shl,   v.a.x, v.a.y);
    o.a.y = max3f(v.a.x, v.a.y, v.a.z);
    o.a.z = max3f(v.a.y, v.a.z, v.a.w);
    o.a.w = max3f(v.a.z, v.a.w, v.b.x);
    o.b.x = max3f(v.a.w, v.b.x, v.b.y);
    o.b.y = max3f(v.b.x, v.b.y, v.b.z);
    o.b.z = max3f(v.b.y, v.b.z, v.b.w);
    o.b.w = max3f(v.b.z, v.b.w, shr);
    return o;
}

// Row-paired skeletonize stage step. Entry: x[0]=x[t-2], x[1]=x[t-1],
// mn[0]=mn[t-3], mn[1]=mn[t-2]. Inputs in0=x[t], in1=x[t+1]. Exit: in0/in1 =
// stage outputs for rows (t-2, t-1), state advanced 2 rows.
// Contour identity: the 3x3 max window contains its center => mp >= mn, so
// relu(mp-mn) == mp-mn bit-exactly on valid rows. NaN paths exist only in
// warmup rows that never reach the output region (IEEE v_max drops NaN).
template <bool EDGE>
static __device__ __forceinline__ void step2(Row (&x)[2], Row (&mn)[2],
                                             Row& in0, Row& in1, int t) {
    Row vmin0 = rmin3(x[0], x[1], in0);      // centered row t-1
    Row vmin1 = rmin3(x[1], in0, in1);       // centered row t
    Row mna = hmin3(vmin0);                  // mn[t-1]
    Row mnb = hmin3(vmin1);                  // mn[t]
    if (EDGE) {
        if ((unsigned)(t - 1) >= IMG) mna = splat(-INF);
        if ((unsigned)t >= IMG) mnb = splat(-INF);
    }
    Row vmax0 = rmax3(mn[0], mn[1], mna);    // centered t-2
    Row vmax1 = rmax3(mn[1], mna, mnb);      // centered t-1
    Row mp0 = hmax3(vmax0);
    Row mp1 = hmax3(vmax1);
    Row out0, out1;
    {
        const float* px0 = (const float*)&x[0];
        const float* px1 = (const float*)&x[1];
        const float* pm1 = (const float*)&mn[1];
        const float* pma = (const float*)&mna;
        const float* pp0 = (const float*)&mp0;
        const float* pp1 = (const float*)&mp1;
        float* po0 = (float*)&out0;
        float* po1 = (float*)&out1;
#pragma unroll
        for (int i = 0; i < 8; ++i) {
            po0[i] = fmaxf(px0[i] - (pp0[i] - pm1[i]), 0.f);
            po1[i] = fmaxf(px1[i] - (pp1[i] - pma[i]), 0.f);
        }
    }
    if (EDGE) {
        if ((unsigned)(t - 2) >= IMG) out0 = splat(INF);
        if ((unsigned)(t - 1) >= IMG) out1 = splat(INF);
    }
    x[0] = in0;  x[1] = in1;
    mn[0] = mna; mn[1] = mnb;
    in0 = out0;  in1 = out1;
}

static __device__ __forceinline__ Row load_or_inf(const float* __restrict__ p, int r, int lane) {
    if ((unsigned)r >= IMG) return splat(INF);
    const float4* q = (const float4*)(p + (size_t)r * IMG + lane * 8);
    Row o;
    o.a = q[0];
    o.b = q[1];
    return o;
}

// ---------------- Launch 1: iterations 0..4, write intermediate ----------------
template <bool EDGE>
static __device__ __forceinline__ void run_a(const float* __restrict__ src,
                                             float* __restrict__ dst, int B, int lane) {
    Row x[NSTG][2], mn[NSTG][2];
#pragma unroll
    for (int j = 0; j < NSTG; ++j) {
        x[j][0] = splat(INF);   x[j][1] = splat(INF);
        mn[j][0] = splat(-INF); mn[j][1] = splat(-INF);
    }
    Row pre0 = load_or_inf(src, B - HALO, lane);
    Row pre1 = load_or_inf(src, B - HALO + 1, lane);
#pragma unroll 2
    for (int k = 0; k < NSTEP; ++k) {
        const int t = B - HALO + 2 * k;
        Row in0 = pre0, in1 = pre1;
        const int tp = (k + 1 < NSTEP) ? t + 2 : -2;
        pre0 = load_or_inf(src, tp, lane);
        pre1 = load_or_inf(src, tp + 1, lane);
#pragma unroll
        for (int j = 0; j < NSTG; ++j)
            step2<EDGE>(x[j], mn[j], in0, in1, t - 2 * j);
        const int v = t - HALO;
        if ((unsigned)(v - B) < BAND) {
            float4* q0 = (float4*)(dst + (size_t)v * IMG + lane * 8);
            q0[0] = in0.a; q0[1] = in0.b;
            float4* q1 = (float4*)(dst + (size_t)(v + 1) * IMG + lane * 8);
            q1[0] = in1.a; q1[1] = in1.b;
        }
    }
}

// Kernel A also zeroes acc/counter for kernel B (stream ordering guarantees
// visibility, same as the mid buffer) — removes the memset node.
__global__ __launch_bounds__(64, 2) void skel5_a(const float* __restrict__ yp,
                                                 const float* __restrict__ yt,
                                                 float* __restrict__ mid,
                                                 double* __restrict__ acc,
                                                 unsigned* __restrict__ counter) {
    const int blk = blockIdx.x;
    if (blk == 0 && threadIdx.x == 0) {
        acc[0] = 0.0; acc[1] = 0.0; acc[2] = 0.0; acc[3] = 0.0;
        *counter = 0u;
    }
    const int img = blk >> 5, band = blk & (NBAND - 1);
    const float* src = (img < NB) ? yp + (size_t)(2 * img + 1) * HW
                                  : yt + (size_t)(2 * (img - NB) + 1) * HW;
    float* dst = mid + (size_t)img * HW;
    const int lane = threadIdx.x;
    const int B = band * BAND;
    if (band == 0 || band == NBAND - 1) run_a<true>(src, dst, B, lane);
    else                                run_a<false>(src, dst, B, lane);
}

// ---------- Launch 2: iterations 5..9 + fused reduction + ticket finalize ----------
template <bool EDGE>
static __device__ __forceinline__ void run_b(const float* __restrict__ src,
                                             const float* __restrict__ wp, int B, int lane,
                                             float& s_prod, float& s_val) {
    Row x[NSTG][2], mn[NSTG][2];
#pragma unroll
    for (int j = 0; j < NSTG; ++j) {
        x[j][0] = splat(INF);   x[j][1] = splat(INF);
        mn[j][0] = splat(-INF); mn[j][1] = splat(-INF);
    }
    Row pre0 = load_or_inf(src, B - HALO, lane);
    Row pre1 = load_or_inf(src, B - HALO + 1, lane);
    Row wb0 = splat(0.f), wb1 = splat(0.f);   // weight rows, prefetched 1 step ahead
#pragma unroll 2
    for (int k = 0; k < NSTEP; ++k) {
        const int t = B - HALO + 2 * k;
        const int v = t - HALO;
        Row in0 = pre0, in1 = pre1;
        const int tp = (k + 1 < NSTEP) ? t + 2 : -2;
        pre0 = load_or_inf(src, tp, lane);
        pre1 = load_or_inf(src, tp + 1, lane);
        const Row w0 = wb0, w1 = wb1;          // loaded during step k-1
        if ((unsigned)(v + 2 - B) < BAND) {    // prefetch rows v+2, v+3
            const float4* q0 = (const float4*)(wp + (size_t)(v + 2) * IMG + lane * 8);
            wb0.a = q0[0]; wb0.b = q0[1];
            const float4* q1 = (const float4*)(wp + (size_t)(v + 3) * IMG + lane * 8);
            wb1.a = q1[0]; wb1.b = q1[1];
        }
#pragma unroll
        for (int j = 0; j < NSTG; ++j)
            step2<EDGE>(x[j], mn[j], in0, in1, t - 2 * j);
        if ((unsigned)(v - B) < BAND) {
            const float* p0 = (const float*)&in0;
            const float* p1 = (const float*)&in1;
            const float* q0 = (const float*)&w0;
            const float* q1 = (const float*)&w1;
#pragma unroll
            for (int i = 0; i < 8; ++i) {
                s_prod += p0[i] * q0[i] + p1[i] * q1[i];
                s_val += p0[i] + p1[i];
            }
        }
    }
}

__global__ __launch_bounds__(64, 2) void skel5_b(const float* __restrict__ mid,
                                                 const float* __restrict__ yp,
                                                 const float* __restrict__ yt,
                                                 double* __restrict__ acc,
                                                 unsigned* __restrict__ counter,
                                                 float* __restrict__ out) {
    const int blk = blockIdx.x;
    const int img = blk >> 5, band = blk & (NBAND - 1);
    const float* src = mid + (size_t)img * HW;
    // skel(pred) pairs with y_true c1; skel(true) pairs with y_pred c1.
    const float* wp = (img < NB) ? yt + (size_t)(2 * img + 1) * HW
                                 : yp + (size_t)(2 * (img - NB) + 1) * HW;
    const int lane = threadIdx.x;
    const int B = band * BAND;

    float s_prod = 0.f, s_val = 0.f;
    if (band == 0 || band == NBAND - 1) run_b<true>(src, wp, B, lane, s_prod, s_val);
    else                                run_b<false>(src, wp, B, lane, s_prod, s_val);

#pragma unroll
    for (int off = 32; off; off >>= 1) {
        s_prod += __shfl_down(s_prod, off);
        s_val += __shfl_down(s_val, off);
    }
    if (lane == 0) {
        const int base = (img < NB) ? 0 : 2;
        atomicAdd(&acc[base], (double)s_prod);
        atomicAdd(&acc[base + 1], (double)s_val);
        __threadfence();
        unsigned ticket = atomicAdd(counter, 1u);
        if (ticket == GRID - 1) {
            // Last block: all acc adds are fenced-before their counter adds,
            // so device-scope RMW reads here see the final values.
            double a0 = atomicAdd(&acc[0], 0.0);
            double a1 = atomicAdd(&acc[1], 0.0);
            double a2 = atomicAdd(&acc[2], 0.0);
            double a3 = atomicAdd(&acc[3], 0.0);
            double tprec = (a0 + 1.0) / (a1 + 1.0);
            double tsens = (a2 + 1.0) / (a3 + 1.0);
            out[0] = (float)(1.0 - 2.0 * (tprec * tsens) / (tprec + tsens));
        }
    }
}

extern "C" void kernel_launch(void* const* d_in, const int* in_sizes, int n_in,
                              void* d_out, int out_size, void* d_ws, size_t ws_size,
                              hipStream_t stream) {
    (void)in_sizes; (void)n_in; (void)out_size; (void)ws_size;
    const float* yp = (const float*)d_in[0];
    const float* yt = (const float*)d_in[1];
    float* out = (float*)d_out;

    // Workspace: mid (64 MB) | acc (4 doubles) | counter (1 u32)
    float* mid = (float*)d_ws;
    double* acc = (double*)(mid + (size_t)NIMG * HW);
    unsigned* counter = (unsigned*)(acc + 4);

    skel5_a<<<GRID, 64, 0, stream>>>(yp, yt, mid, acc, counter);
    skel5_b<<<GRID, 64, 0, stream>>>(mid, yp, yt, acc, counter, out);
}

// Round 8
// 296.797 us; speedup vs baseline: 1.4001x; 1.4001x over previous
//
#include <hip/hip_runtime.h>

#define IMG 512
#define HW (IMG * IMG)
#define NB 32
#define NIMG 64
#define BAND 16
#define NBAND (IMG / BAND)              // 32
#define GRID (NIMG * NBAND)             // 2048
#define NSTG 5                          // fused iterations per launch
#define HALO (2 * NSTG)                 // 10
#define NSTEP ((BAND + 2 * HALO) / 2)   // 18 row-pair steps
#define INF __builtin_inff()

// DPP whole-wave shift-by-1. bound_ctrl=0 keeps `ident` (old) in the vacated lane.
static __device__ __forceinline__ float dpp_from_prev(float v, float ident) {
    return __int_as_float(__builtin_amdgcn_update_dpp(
        __float_as_int(ident), __float_as_int(v), 0x138, 0xF, 0xF, false));
}
static __device__ __forceinline__ float dpp_from_next(float v, float ident) {
    return __int_as_float(__builtin_amdgcn_update_dpp(
        __float_as_int(ident), __float_as_int(v), 0x130, 0xF, 0xF, false));
}

// One lane owns 8 contiguous columns: a = cols[8l..8l+3], b = cols[8l+4..8l+7].
struct Row { float4 a, b; };

static __device__ __forceinline__ float min3f(float a, float b, float c) { return fminf(fminf(a, b), c); }
static __device__ __forceinline__ float max3f(float a, float b, float c) { return fmaxf(fmaxf(a, b), c); }

static __device__ __forceinline__ Row splat(float v) {
    Row r;
    r.a = make_float4(v, v, v, v);
    r.b = make_float4(v, v, v, v);
    return r;
}

static __device__ __forceinline__ Row rmin3(const Row& x, const Row& y, const Row& z) {
    Row o;
    const float* px = (const float*)&x;
    const float* py = (const float*)&y;
    const float* pz = (const float*)&z;
    float* po = (float*)&o;
#pragma unroll
    for (int i = 0; i < 8; ++i) po[i] = min3f(px[i], py[i], pz[i]);
    return o;
}

static __device__ __forceinline__ Row rmax3(const Row& x, const Row& y, const Row& z) {
    Row o;
    const float* px = (const float*)&x;
    const float* py = (const float*)&y;
    const float* pz = (const float*)&z;
    float* po = (float*)&o;
#pragma unroll
    for (int i = 0; i < 8; ++i) po[i] = max3f(px[i], py[i], pz[i]);
    return o;
}

static __device__ __forceinline__ Row hmin3(const Row& v) {
    float shl = dpp_from_prev(v.b.w, INF);
    float shr = dpp_from_next(v.a.x, INF);
    Row o;
    o.a.x = min3f(shl,   v.a.x, v.a.y);
    o.a.y = min3f(v.a.x, v.a.y, v.a.z);
    o.a.z = min3f(v.a.y, v.a.z, v.a.w);
    o.a.w = min3f(v.a.z, v.a.w, v.b.x);
    o.b.x = min3f(v.a.w, v.b.x, v.b.y);
    o.b.y = min3f(v.b.x, v.b.y, v.b.z);
    o.b.z = min3f(v.b.y, v.b.z, v.b.w);
    o.b.w = min3f(v.b.z, v.b.w, shr);
    return o;
}

static __device__ __forceinline__ Row hmax3(const Row& v) {
    float shl = dpp_from_prev(v.b.w, -INF);
    float shr = dpp_from_next(v.a.x, -INF);
    Row o;
    o.a.x = max3f(shl,   v.a.x, v.a.y);
    o.a.y = max3f(v.a.x, v.a.y, v.a.z);
    o.a.z = max3f(v.a.y, v.a.z, v.a.w);
    o.a.w = max3f(v.a.z, v.a.w, v.b.x);
    o.b.x = max3f(v.a.w, v.b.x, v.b.y);
    o.b.y = max3f(v.b.x, v.b.y, v.b.z);
    o.b.z = max3f(v.b.y, v.b.z, v.b.w);
    o.b.w = max3f(v.b.z, v.b.w, shr);
    return o;
}

// Row-paired skeletonize stage step. Entry: x[0]=x[t-2], x[1]=x[t-1],
// mn[0]=mn[t-3], mn[1]=mn[t-2]. Inputs in0=x[t], in1=x[t+1]. Exit: in0/in1 =
// stage outputs for rows (t-2, t-1), state advanced 2 rows.
// Contour identity: the 3x3 max window contains its center => mp >= mn, so
// relu(mp-mn) == mp-mn bit-exactly on valid rows. NaN paths exist only in
// warmup rows that never reach the output region (IEEE v_max drops NaN).
template <bool EDGE>
static __device__ __forceinline__ void step2(Row (&x)[2], Row (&mn)[2],
                                             Row& in0, Row& in1, int t) {
    Row vmin0 = rmin3(x[0], x[1], in0);      // centered row t-1
    Row vmin1 = rmin3(x[1], in0, in1);       // centered row t
    Row mna = hmin3(vmin0);                  // mn[t-1]
    Row mnb = hmin3(vmin1);                  // mn[t]
    if (EDGE) {
        if ((unsigned)(t - 1) >= IMG) mna = splat(-INF);
        if ((unsigned)t >= IMG) mnb = splat(-INF);
    }
    Row vmax0 = rmax3(mn[0], mn[1], mna);    // centered t-2
    Row vmax1 = rmax3(mn[1], mna, mnb);      // centered t-1
    Row mp0 = hmax3(vmax0);
    Row mp1 = hmax3(vmax1);
    Row out0, out1;
    {
        const float* px0 = (const float*)&x[0];
        const float* px1 = (const float*)&x[1];
        const float* pm1 = (const float*)&mn[1];
        const float* pma = (const float*)&mna;
        const float* pp0 = (const float*)&mp0;
        const float* pp1 = (const float*)&mp1;
        float* po0 = (float*)&out0;
        float* po1 = (float*)&out1;
#pragma unroll
        for (int i = 0; i < 8; ++i) {
            po0[i] = fmaxf(px0[i] - (pp0[i] - pm1[i]), 0.f);
            po1[i] = fmaxf(px1[i] - (pp1[i] - pma[i]), 0.f);
        }
    }
    if (EDGE) {
        if ((unsigned)(t - 2) >= IMG) out0 = splat(INF);
        if ((unsigned)(t - 1) >= IMG) out1 = splat(INF);
    }
    x[0] = in0;  x[1] = in1;
    mn[0] = mna; mn[1] = mnb;
    in0 = out0;  in1 = out1;
}

static __device__ __forceinline__ Row load_or_inf(const float* __restrict__ p, int r, int lane) {
    if ((unsigned)r >= IMG) return splat(INF);
    const float4* q = (const float4*)(p + (size_t)r * IMG + lane * 8);
    Row o;
    o.a = q[0];
    o.b = q[1];
    return o;
}

// ---------------- Launch 1: iterations 0..4, write intermediate ----------------
template <bool EDGE>
static __device__ __forceinline__ void run_a(const float* __restrict__ src,
                                             float* __restrict__ dst, int B, int lane) {
    Row x[NSTG][2], mn[NSTG][2];
#pragma unroll
    for (int j = 0; j < NSTG; ++j) {
        x[j][0] = splat(INF);   x[j][1] = splat(INF);
        mn[j][0] = splat(-INF); mn[j][1] = splat(-INF);
    }
    Row pre0 = load_or_inf(src, B - HALO, lane);
    Row pre1 = load_or_inf(src, B - HALO + 1, lane);
    // unroll 1: live state must stay within one iteration — unroll 2 spilled
    // the pipeline to scratch (R7: WRITE_SIZE 0.13 MB -> 289 MB, 2x regression).
#pragma unroll 1
    for (int k = 0; k < NSTEP; ++k) {
        const int t = B - HALO + 2 * k;
        Row in0 = pre0, in1 = pre1;
        const int tp = (k + 1 < NSTEP) ? t + 2 : -2;
        pre0 = load_or_inf(src, tp, lane);
        pre1 = load_or_inf(src, tp + 1, lane);
#pragma unroll
        for (int j = 0; j < NSTG; ++j)
            step2<EDGE>(x[j], mn[j], in0, in1, t - 2 * j);
        const int v = t - HALO;
        if ((unsigned)(v - B) < BAND) {
            float4* q0 = (float4*)(dst + (size_t)v * IMG + lane * 8);
            q0[0] = in0.a; q0[1] = in0.b;
            float4* q1 = (float4*)(dst + (size_t)(v + 1) * IMG + lane * 8);
            q1[0] = in1.a; q1[1] = in1.b;
        }
    }
}

// Kernel A also zeroes acc/counter for kernel B (stream ordering guarantees
// visibility, same as the mid buffer) — removes the memset node.
__global__ __launch_bounds__(64, 2) void skel5_a(const float* __restrict__ yp,
                                                 const float* __restrict__ yt,
                                                 float* __restrict__ mid,
                                                 double* __restrict__ acc,
                                                 unsigned* __restrict__ counter) {
    const int blk = blockIdx.x;
    if (blk == 0 && threadIdx.x == 0) {
        acc[0] = 0.0; acc[1] = 0.0; acc[2] = 0.0; acc[3] = 0.0;
        *counter = 0u;
    }
    const int img = blk >> 5, band = blk & (NBAND - 1);
    const float* src = (img < NB) ? yp + (size_t)(2 * img + 1) * HW
                                  : yt + (size_t)(2 * (img - NB) + 1) * HW;
    float* dst = mid + (size_t)img * HW;
    const int lane = threadIdx.x;
    const int B = band * BAND;
    if (band == 0 || band == NBAND - 1) run_a<true>(src, dst, B, lane);
    else                                run_a<false>(src, dst, B, lane);
}

// ---------- Launch 2: iterations 5..9 + fused reduction + ticket finalize ----------
template <bool EDGE>
static __device__ __forceinline__ void run_b(const float* __restrict__ src,
                                             const float* __restrict__ wp, int B, int lane,
                                             float& s_prod, float& s_val) {
    Row x[NSTG][2], mn[NSTG][2];
#pragma unroll
    for (int j = 0; j < NSTG; ++j) {
        x[j][0] = splat(INF);   x[j][1] = splat(INF);
        mn[j][0] = splat(-INF); mn[j][1] = splat(-INF);
    }
    Row pre0 = load_or_inf(src, B - HALO, lane);
    Row pre1 = load_or_inf(src, B - HALO + 1, lane);
    Row wb0 = splat(0.f), wb1 = splat(0.f);   // weight rows, prefetched 1 step ahead
#pragma unroll 1
    for (int k = 0; k < NSTEP; ++k) {
        const int t = B - HALO + 2 * k;
        const int v = t - HALO;
        Row in0 = pre0, in1 = pre1;
        const int tp = (k + 1 < NSTEP) ? t + 2 : -2;
        pre0 = load_or_inf(src, tp, lane);
        pre1 = load_or_inf(src, tp + 1, lane);
        const Row w0 = wb0, w1 = wb1;          // loaded during step k-1
        if ((unsigned)(v + 2 - B) < BAND) {    // prefetch rows v+2, v+3
            const float4* q0 = (const float4*)(wp + (size_t)(v + 2) * IMG + lane * 8);
            wb0.a = q0[0]; wb0.b = q0[1];
            const float4* q1 = (const float4*)(wp + (size_t)(v + 3) * IMG + lane * 8);
            wb1.a = q1[0]; wb1.b = q1[1];
        }
#pragma unroll
        for (int j = 0; j < NSTG; ++j)
            step2<EDGE>(x[j], mn[j], in0, in1, t - 2 * j);
        if ((unsigned)(v - B) < BAND) {
            const float* p0 = (const float*)&in0;
            const float* p1 = (const float*)&in1;
            const float* q0 = (const float*)&w0;
            const float* q1 = (const float*)&w1;
#pragma unroll
            for (int i = 0; i < 8; ++i) {
                s_prod += p0[i] * q0[i] + p1[i] * q1[i];
                s_val += p0[i] + p1[i];
            }
        }
    }
}

__global__ __launch_bounds__(64, 2) void skel5_b(const float* __restrict__ mid,
                                                 const float* __restrict__ yp,
                                                 const float* __restrict__ yt,
                                                 double* __restrict__ acc,
                                                 unsigned* __restrict__ counter,
                                                 float* __restrict__ out) {
    const int blk = blockIdx.x;
    const int img = blk >> 5, band = blk & (NBAND - 1);
    const float* src = mid + (size_t)img * HW;
    // skel(pred) pairs with y_true c1; skel(true) pairs with y_pred c1.
    const float* wp = (img < NB) ? yt + (size_t)(2 * img + 1) * HW
                                 : yp + (size_t)(2 * (img - NB) + 1) * HW;
    const int lane = threadIdx.x;
    const int B = band * BAND;

    float s_prod = 0.f, s_val = 0.f;
    if (band == 0 || band == NBAND - 1) run_b<true>(src, wp, B, lane, s_prod, s_val);
    else                                run_b<false>(src, wp, B, lane, s_prod, s_val);

#pragma unroll
    for (int off = 32; off; off >>= 1) {
        s_prod += __shfl_down(s_prod, off);
        s_val += __shfl_down(s_val, off);
    }
    if (lane == 0) {
        const int base = (img < NB) ? 0 : 2;
        atomicAdd(&acc[base], (double)s_prod);
        atomicAdd(&acc[base + 1], (double)s_val);
        __threadfence();
        unsigned ticket = atomicAdd(counter, 1u);
        if (ticket == GRID - 1) {
            // Last block: all acc adds are fenced-before their counter adds,
            // so device-scope RMW reads here see the final values.
            double a0 = atomicAdd(&acc[0], 0.0);
            double a1 = atomicAdd(&acc[1], 0.0);
            double a2 = atomicAdd(&acc[2], 0.0);
            double a3 = atomicAdd(&acc[3], 0.0);
            double tprec = (a0 + 1.0) / (a1 + 1.0);
            double tsens = (a2 + 1.0) / (a3 + 1.0);
            out[0] = (float)(1.0 - 2.0 * (tprec * tsens) / (tprec + tsens));
        }
    }
}

extern "C" void kernel_launch(void* const* d_in, const int* in_sizes, int n_in,
                              void* d_out, int out_size, void* d_ws, size_t ws_size,
                              hipStream_t stream) {
    (void)in_sizes; (void)n_in; (void)out_size; (void)ws_size;
    const float* yp = (const float*)d_in[0];
    const float* yt = (const float*)d_in[1];
    float* out = (float*)d_out;

    // Workspace: mid (64 MB) | acc (4 doubles) | counter (1 u32)
    float* mid = (float*)d_ws;
    double* acc = (double*)(mid + (size_t)NIMG * HW);
    unsigned* counter = (unsigned*)(acc + 4);

    skel5_a<<<GRID, 64, 0, stream>>>(yp, yt, mid, acc, counter);
    skel5_b<<<GRID, 64, 0, stream>>>(mid, yp, yt, acc, counter, out);
}